// Round 1
// baseline (3183.585 us; speedup 1.0000x reference)
//
#include <hip/hip_runtime.h>
#include <cmath>

// ---------------------------------------------------------------------------
// Down_42468636623217 — round 0 baseline (all fp32, no MFMA yet).
// Pipeline: pre(DWT+transpose) -> conv1 GEMM -> conv4x4 -> QK GEMM -> colmax
//           -> expsum -> PV GEMM (exp/recl folded into loaders) -> FFN
//           (6 GEMMs + 3 LN) -> combine (inline bilinear resize + transpose).
// ---------------------------------------------------------------------------

#define EPI_NONE 0
#define EPI_GELU 1
#define EPI_GELU_SUB 2
#define EPI_ADD 3
#define EPI_SIGMOID 4

__device__ __forceinline__ float gelu_f(float v) {
  return 0.5f * v * (1.f + erff(v * 0.70710678118654752f));
}
__device__ __forceinline__ float sigmoid_f(float v) {
  return 1.f / (1.f + __expf(-v));
}

// --------------------------- DWT + transpose -------------------------------
// x: (16,128,128,128) NCHW fp32.  Outputs token-major (b, t=64*64, c):
//   yL  = (a+b+c+d)/2, yHH = (a-b-c+d)/2
//   hllh: 256-wide, [0:128]=HL=(a-b+c-d)/2, [128:256]=LH=(a+b-c-d)/2
__global__ __launch_bounds__(256) void pre_k(const float* __restrict__ x,
                                             float* __restrict__ yL,
                                             float* __restrict__ yHH,
                                             float* __restrict__ hllh) {
  int gx = blockIdx.x;            // grid.x = 2 (jt) * 4 (ci tile) = 8
  int jt = gx & 1, cit = gx >> 1;
  int i = blockIdx.y, b = blockIdx.z;
  int j0 = jt * 32, ci0 = cit * 32;
  int tx = threadIdx.x & 31, ty = threadIdx.x >> 5;
  __shared__ float sll[32][33], shl[32][33], slh[32][33], shh[32][33];
  const float2* x2 = (const float2*)x;
#pragma unroll
  for (int k = 0; k < 4; ++k) {
    int ci = ty + 8 * k;
    long base = (((long)b * 128 + ci0 + ci) * 128 + 2 * i) * 64 + j0 + tx;
    float2 ab = x2[base];
    float2 cd = x2[base + 64];
    float a = ab.x, bb = ab.y, c = cd.x, d = cd.y;
    sll[ci][tx] = (a + bb + c + d) * 0.5f;
    shl[ci][tx] = (a - bb + c - d) * 0.5f;
    slh[ci][tx] = (a + bb - c - d) * 0.5f;
    shh[ci][tx] = (a - bb - c + d) * 0.5f;
  }
  __syncthreads();
  long tok = (long)b * 4096 + i * 64 + j0;
#pragma unroll
  for (int k = 0; k < 4; ++k) {
    int row = ty + 8 * k;  // token offset within j-tile
    long t = tok + row;
    yL[t * 128 + ci0 + tx] = sll[tx][row];
    yHH[t * 128 + ci0 + tx] = shh[tx][row];
    hllh[t * 256 + ci0 + tx] = shl[tx][row];
    hllh[t * 256 + 128 + ci0 + tx] = slh[tx][row];
  }
}

// ------------------------------- GEMM --------------------------------------
// C[m,n] = alpha * sum_k A[m,k] * Bmat + bias[n], tile 64x64, TK=32.
// BT=true : B row-major N x K (contract over fast axis)  -> x @ W^T
// BT=false: B row-major K x N (contract over rows)       -> P @ V
// AEXP  : A element -> exp(A - amax[z*512 + k])  (softmax numerator)
// BSCALE: B row k scaled by rls[z*512 + k]       (1/l_k folded into V)
template <bool BT, bool AEXP, bool BSCALE, int EPI>
__global__ __launch_bounds__(256) void gemm_k(
    const float* __restrict__ A, long sA, int lda,
    const float* __restrict__ B, long sB, int ldb,
    float* __restrict__ C, long sC, int ldc,
    int K, float alpha,
    const float* __restrict__ bias,
    const float* __restrict__ aux,
    const float* __restrict__ amax,
    const float* __restrict__ rls) {
  __shared__ float As[32][68];  // [k][m], stride 68 keeps float4 reads aligned
  __shared__ float Bs[32][68];  // [k][n]
  int z = blockIdx.z;
  const float* Ab = A + (long)z * sA;
  const float* Bb = B + (long)z * sB;
  float* Cb = C + (long)z * sC;
  int m0 = blockIdx.x * 64, n0 = blockIdx.y * 64;
  int tid = threadIdx.x;
  int tx = tid & 15, ty = tid >> 4;
  float acc[4][4] = {};
  for (int k0 = 0; k0 < K; k0 += 32) {
#pragma unroll
    for (int u = 0; u < 8; ++u) {
      int f = tid * 8 + u;
      int r = f >> 5, kk = f & 31;
      float v = Ab[(long)(m0 + r) * lda + k0 + kk];
      if (AEXP) v = __expf(v - amax[(long)z * 512 + k0 + kk]);
      As[kk][r] = v;
    }
    if (BT) {
#pragma unroll
      for (int u = 0; u < 8; ++u) {
        int f = tid * 8 + u;
        int r = f >> 5, kk = f & 31;
        Bs[kk][r] = Bb[(long)(n0 + r) * ldb + k0 + kk];
      }
    } else {
#pragma unroll
      for (int u = 0; u < 8; ++u) {
        int f = u * 256 + tid;
        int n = f & 63, kk = f >> 6;
        float v = Bb[(long)(k0 + kk) * ldb + n0 + n];
        if (BSCALE) v *= rls[(long)z * 512 + k0 + kk];
        Bs[kk][n] = v;
      }
    }
    __syncthreads();
#pragma unroll
    for (int kk = 0; kk < 32; ++kk) {
      float4 a4 = *(const float4*)&As[kk][ty * 4];
      float4 b4 = *(const float4*)&Bs[kk][tx * 4];
      acc[0][0] += a4.x * b4.x; acc[0][1] += a4.x * b4.y; acc[0][2] += a4.x * b4.z; acc[0][3] += a4.x * b4.w;
      acc[1][0] += a4.y * b4.x; acc[1][1] += a4.y * b4.y; acc[1][2] += a4.y * b4.z; acc[1][3] += a4.y * b4.w;
      acc[2][0] += a4.z * b4.x; acc[2][1] += a4.z * b4.y; acc[2][2] += a4.z * b4.z; acc[2][3] += a4.z * b4.w;
      acc[3][0] += a4.w * b4.x; acc[3][1] += a4.w * b4.y; acc[3][2] += a4.w * b4.z; acc[3][3] += a4.w * b4.w;
    }
    __syncthreads();
  }
#pragma unroll
  for (int i = 0; i < 4; ++i) {
    int m = m0 + ty * 4 + i;
#pragma unroll
    for (int j = 0; j < 4; ++j) {
      int n = n0 + tx * 4 + j;
      float v = acc[i][j] * alpha;
      if (bias) v += bias[n];
      if (EPI == EPI_GELU) v = gelu_f(v);
      else if (EPI == EPI_GELU_SUB) v = gelu_f(v) - aux[(long)m * ldc + n];
      else if (EPI == EPI_ADD) v += aux[(long)m * ldc + n];
      else if (EPI == EPI_SIGMOID) v = sigmoid_f(v);
      Cb[(long)m * ldc + n] = v;
    }
  }
}

// ------------------------ conv 4x4 stride 2, pad 1 -------------------------
// dw[b,co,i,j] = relu( sum_{ci,kh,kw} x[b,ci,2i-1+kh,2j-1+kw]*w[co,ci,kh,kw] + b[co] )
// Block: 32 co x 4 i x 32 j for one b. ci chunked by 8 through LDS.
__global__ __launch_bounds__(256) void conv4_k(const float* __restrict__ x,
                                               const float* __restrict__ w,
                                               const float* __restrict__ bias,
                                               float* __restrict__ dw) {
  int gx = blockIdx.x;               // 2 (jt) * 16 (it) * 4 (cot) = 128
  int jt = gx & 1;
  int it = (gx >> 1) & 15;
  int cot = gx >> 5;
  int b = blockIdx.y;
  int j0 = jt * 32, i0 = it * 4, co0 = cot * 32;
  __shared__ float xs[8][10][66];          // rows 2i0-1..2i0+8, cols 2j0-1..2j0+64
  __shared__ float4 wf4[32][8][4];         // [co][ci][kh] -> kw packed in float4
  int tid = threadIdx.x;
  int tx = tid & 31, cg = tid >> 5;
  float acc[4][4] = {};  // [i][co-group]
  for (int c0 = 0; c0 < 128; c0 += 8) {
    for (int f = tid; f < 8 * 10 * 66; f += 256) {
      int ci = f / 660;
      int rem = f - ci * 660;
      int r = rem / 66, cc = rem - r * 66;
      int gr = 2 * i0 - 1 + r, gc = 2 * j0 - 1 + cc;
      float v = 0.f;
      if ((unsigned)gr < 128u && (unsigned)gc < 128u)
        v = x[(((long)b * 128 + c0 + ci) * 128 + gr) * 128 + gc];
      xs[ci][r][cc] = v;
    }
    for (int f = tid; f < 1024; f += 256) {
      int co = f >> 5;
      int rest = f & 31;
      int ci = rest >> 2, kh = rest & 3;
      wf4[co][ci][kh] = ((const float4*)w)[(((long)(co0 + co) * 128) + c0 + ci) * 4 + kh];
    }
    __syncthreads();
#pragma unroll
    for (int ci = 0; ci < 8; ++ci) {
#pragma unroll
      for (int kh = 0; kh < 4; ++kh) {
        float4 w0 = wf4[cg][ci][kh];
        float4 w1 = wf4[cg + 8][ci][kh];
        float4 w2 = wf4[cg + 16][ci][kh];
        float4 w3 = wf4[cg + 24][ci][kh];
#pragma unroll
        for (int i = 0; i < 4; ++i) {
          const float* xr = &xs[ci][2 * i + kh][2 * tx];
          float2 xa = *(const float2*)xr;
          float2 xb = *(const float2*)(xr + 2);
          acc[i][0] += xa.x * w0.x + xa.y * w0.y + xb.x * w0.z + xb.y * w0.w;
          acc[i][1] += xa.x * w1.x + xa.y * w1.y + xb.x * w1.z + xb.y * w1.w;
          acc[i][2] += xa.x * w2.x + xa.y * w2.y + xb.x * w2.z + xb.y * w2.w;
          acc[i][3] += xa.x * w3.x + xa.y * w3.y + xb.x * w3.z + xb.y * w3.w;
        }
      }
    }
    __syncthreads();
  }
#pragma unroll
  for (int i = 0; i < 4; ++i) {
#pragma unroll
    for (int k = 0; k < 4; ++k) {
      int co = co0 + cg + 8 * k;
      float v = fmaxf(acc[i][k] + bias[co], 0.f);
      dw[(((long)b * 128 + co) * 64 + i0 + i) * 64 + j0 + tx] = v;
    }
  }
}

// ------------------- attention column-softmax statistics -------------------
__global__ __launch_bounds__(256) void colmax_k(const float* __restrict__ S,
                                                float* __restrict__ cmax) {
  int z = blockIdx.y;
  int k = blockIdx.x * 256 + threadIdx.x;
  const float* Sb = S + (long)z * 262144;
  float m = -3.4e38f;
#pragma unroll 8
  for (int q = 0; q < 512; ++q) m = fmaxf(m, Sb[(long)q * 512 + k]);
  cmax[(long)z * 512 + k] = m;
}

__global__ __launch_bounds__(256) void expsum_k(const float* __restrict__ S,
                                                const float* __restrict__ cmax,
                                                float* __restrict__ recl) {
  int z = blockIdx.y;
  int k = blockIdx.x * 256 + threadIdx.x;
  const float* Sb = S + (long)z * 262144;
  float mx = cmax[(long)z * 512 + k];
  float s = 0.f;
#pragma unroll 8
  for (int q = 0; q < 512; ++q) s += __expf(Sb[(long)q * 512 + k] - mx);
  recl[(long)z * 512 + k] = 1.f / s;
}

// ------------------------------ layernorm ----------------------------------
// One wave64 per token (128 channels -> 2 per lane). Optional gate multiply.
__global__ __launch_bounds__(256) void ln_k(const float* __restrict__ X,
                                            const float* __restrict__ g,
                                            const float* __restrict__ bt,
                                            const float* __restrict__ gate,
                                            float* __restrict__ Y) {
  int t = (blockIdx.x * 256 + threadIdx.x) >> 6;
  int lane = threadIdx.x & 63;
  const float* xr = X + (long)t * 128;
  float v0 = xr[lane], v1 = xr[lane + 64];
  float s = v0 + v1, sq = v0 * v0 + v1 * v1;
#pragma unroll
  for (int off = 32; off > 0; off >>= 1) {
    s += __shfl_xor(s, off);
    sq += __shfl_xor(sq, off);
  }
  float mean = s * 0.0078125f;
  float var = sq * 0.0078125f - mean * mean;
  float rstd = rsqrtf(var + 1e-5f);
  float y0 = (v0 - mean) * rstd * g[lane] + bt[lane];
  float y1 = (v1 - mean) * rstd * g[lane + 64] + bt[lane + 64];
  if (gate) {
    y0 *= gate[(long)t * 128 + lane];
    y1 *= gate[(long)t * 128 + lane + 64];
  }
  Y[(long)t * 128 + lane] = y0;
  Y[(long)t * 128 + lane + 64] = y1;
}

// ------------------------------ combine ------------------------------------
// out[b,co,i,j] = attf[b,t,co]*(bilinear(x)[b,co,i,j] - dw[b,co,i,j]) + y[b,t,co]
// token-major att/y loaded via LDS transpose so both sides stay coalesced.
__global__ __launch_bounds__(256) void combine_k(const float* __restrict__ attf,
                                                 const float* __restrict__ yt,
                                                 const float* __restrict__ dw,
                                                 const float* __restrict__ x,
                                                 float* __restrict__ out) {
  int gx = blockIdx.x;  // 2 (jt) * 4 (cot) = 8
  int jt = gx & 1, cot = gx >> 1;
  int i = blockIdx.y, b = blockIdx.z;
  int j0 = jt * 32, co0 = cot * 32;
  int tx = threadIdx.x & 31, ty = threadIdx.x >> 5;
  __shared__ float sa[32][33], sy[32][33];
  long tokbase = (long)b * 4096 + i * 64 + j0;
#pragma unroll
  for (int k = 0; k < 4; ++k) {
    int row = ty + 8 * k;
    long idx = (tokbase + row) * 128 + co0 + tx;
    sa[row][tx] = attf[idx];
    sy[row][tx] = yt[idx];
  }
  __syncthreads();
  float py = (float)(i * 127) / 63.0f;
  int y0 = (int)py;
  int y1 = min(y0 + 1, 127);
  float wy = py - (float)y0;
  int j = j0 + tx;
  float px = (float)(j * 127) / 63.0f;
  int x0 = (int)px;
  int x1 = min(x0 + 1, 127);
  float wx = px - (float)x0;
#pragma unroll
  for (int k = 0; k < 4; ++k) {
    int co = co0 + ty + 8 * k;
    const float* xb = x + (((long)b * 128 + co) * 128) * 128;
    float r0 = xb[y0 * 128 + x0] * (1.f - wx) + xb[y0 * 128 + x1] * wx;
    float r1 = xb[y1 * 128 + x0] * (1.f - wx) + xb[y1 * 128 + x1] * wx;
    float d2 = r0 * (1.f - wy) + r1 * wy;
    long oidx = (((long)b * 128 + co) * 64 + i) * 64 + j;
    float dwv = dw[oidx];
    float av = sa[tx][ty + 8 * k];
    float yv = sy[tx][ty + 8 * k];
    out[oidx] = av * (d2 - dwv) + yv;
  }
}

// ---------------------------------------------------------------------------
extern "C" void kernel_launch(void* const* d_in, const int* in_sizes, int n_in,
                              void* d_out, int out_size, void* d_ws, size_t ws_size,
                              hipStream_t stream) {
  const float* x = (const float*)d_in[0];
  const float* w1 = (const float*)d_in[1];
  const float* b1 = (const float*)d_in[2];
  const float* l1w = (const float*)d_in[3];
  const float* l1b = (const float*)d_in[4];
  const float* ln1g = (const float*)d_in[5];
  const float* ln1b = (const float*)d_in[6];
  const float* fc1w = (const float*)d_in[7];
  const float* fc1b = (const float*)d_in[8];
  const float* divw = (const float*)d_in[9];
  const float* divb = (const float*)d_in[10];
  const float* fc2w = (const float*)d_in[11];
  const float* fc2b = (const float*)d_in[12];
  const float* ln3g = (const float*)d_in[13];
  const float* ln3b = (const float*)d_in[14];
  const float* fc3aw = (const float*)d_in[15];
  const float* fc3ab = (const float*)d_in[16];
  const float* fc3bw = (const float*)d_in[17];
  const float* fc3bb = (const float*)d_in[18];
  const float* lnng = (const float*)d_in[19];
  const float* lnnb = (const float*)d_in[20];
  const float* actw = (const float*)d_in[21];
  const float* actb = (const float*)d_in[22];

  float* ws = (float*)d_ws;
  const long F = 8388608;  // 16*4096*128
  float* yL = ws;            // [0,F)   later t1
  float* yHH = ws + F;       // [F,2F)  later t3
  float* y = ws + 2 * F;     // live till combine
  float* dw = ws + 3 * F;    // live till combine
  float* S = ws + 4 * F;     // [4F,8F)
  float* hllh = ws + 4 * F;  // [4F,6F) dead before S is written
  float* t2 = ws + 4 * F;    // reuse S region after PV
  float* t4 = ws + 5 * F;
  float* attO = ws + 8 * F;  // [8F,9F)
  float* cmax = ws + 9 * F;
  float* recl = ws + 9 * F + 65536;
  float* t1 = yL;
  float* t3 = yHH;

  dim3 blk(256);
  const float qk_scale = 0.35355339059327373f;  // 8^-0.5

  // 1. DWT + transpose
  pre_k<<<dim3(8, 64, 16), blk, 0, stream>>>(x, yL, yHH, hllh);
  // 2. conv1 (1x1, 256->128): y = hllh @ w1^T + b1
  gemm_k<true, false, false, EPI_NONE><<<dim3(1024, 2, 1), blk, 0, stream>>>(
      hllh, 0, 256, w1, 0, 256, y, 0, 128, 256, 1.f, b1, nullptr, nullptr, nullptr);
  // 3. conv4x4 stride2 + relu -> dw (NCHW)
  conv4_k<<<dim3(128, 16), blk, 0, stream>>>(x, l1w, l1b, dw);
  // 4. S = (yL @ y^T) * scale, batched over 128 (b,n) chunks
  gemm_k<true, false, false, EPI_NONE><<<dim3(8, 8, 128), blk, 0, stream>>>(
      yL, 65536, 128, y, 65536, 128, S, 262144, 512, 128, qk_scale,
      nullptr, nullptr, nullptr, nullptr);
  // 5. column (q-axis) softmax stats
  colmax_k<<<dim3(2, 128), blk, 0, stream>>>(S, cmax);
  expsum_k<<<dim3(2, 128), blk, 0, stream>>>(S, cmax, recl);
  // 6. attO = exp(S - m_k) @ (V * 1/l_k)
  gemm_k<false, true, true, EPI_NONE><<<dim3(8, 2, 128), blk, 0, stream>>>(
      S, 262144, 512, yHH, 65536, 128, attO, 65536, 128, 512, 1.f,
      nullptr, nullptr, cmax, recl);
  // 7. FFN
  ln_k<<<16384, blk, 0, stream>>>(attO, ln1g, ln1b, nullptr, t1);
  gemm_k<true, false, false, EPI_GELU><<<dim3(1024, 2, 1), blk, 0, stream>>>(
      t1, 0, 128, fc1w, 0, 128, t2, 0, 128, 128, 1.f, fc1b, nullptr, nullptr, nullptr);
  gemm_k<true, false, false, EPI_GELU_SUB><<<dim3(1024, 2, 1), blk, 0, stream>>>(
      attO, 0, 128, divw, 0, 128, t3, 0, 128, 128, 1.f, divb, t2, nullptr, nullptr);
  gemm_k<true, false, false, EPI_GELU><<<dim3(1024, 2, 1), blk, 0, stream>>>(
      t3, 0, 128, fc2w, 0, 128, t4, 0, 128, 128, 1.f, fc2b, nullptr, nullptr, nullptr);
  ln_k<<<16384, blk, 0, stream>>>(attO, ln3g, ln3b, nullptr, t1);
  gemm_k<true, false, false, EPI_GELU><<<dim3(1024, 2, 1), blk, 0, stream>>>(
      t1, 0, 128, fc3aw, 0, 128, t3, 0, 128, 128, 1.f, fc3ab, nullptr, nullptr, nullptr);
  gemm_k<true, false, false, EPI_ADD><<<dim3(1024, 2, 1), blk, 0, stream>>>(
      t3, 0, 128, fc3bw, 0, 128, t1, 0, 128, 128, 1.f, fc3bb, t4, nullptr, nullptr);
  gemm_k<true, false, false, EPI_SIGMOID><<<dim3(1024, 2, 1), blk, 0, stream>>>(
      attO, 0, 128, actw, 0, 128, t3, 0, 128, 128, 1.f, actb, nullptr, nullptr, nullptr);
  ln_k<<<16384, blk, 0, stream>>>(t1, lnng, lnnb, t3, t2);
  // 8. combine: out = attf * (resize(x) - dw) + y
  combine_k<<<dim3(8, 64, 16), blk, 0, stream>>>(t2, y, dw, x, (float*)d_out);
}

// Round 2
// 1177.273 us; speedup vs baseline: 2.7042x; 2.7042x over previous
//
#include <hip/hip_runtime.h>
#include <cmath>

// ---------------------------------------------------------------------------
// Down_42468636623217 — round 1: conv4x4 -> bf16 MFMA implicit-im2col GEMM.
// Rest of pipeline unchanged from round 0 (passed, absmax 1.6e-2).
// ---------------------------------------------------------------------------

#define EPI_NONE 0
#define EPI_GELU 1
#define EPI_GELU_SUB 2
#define EPI_ADD 3
#define EPI_SIGMOID 4

typedef __bf16 v8bf __attribute__((ext_vector_type(8)));
typedef float f32x4 __attribute__((ext_vector_type(4)));

__device__ __forceinline__ float gelu_f(float v) {
  return 0.5f * v * (1.f + erff(v * 0.70710678118654752f));
}
__device__ __forceinline__ float sigmoid_f(float v) {
  return 1.f / (1.f + __expf(-v));
}
__device__ __forceinline__ unsigned f2bf_pk(float lo, float hi) {
  unsigned a = __float_as_uint(lo), b = __float_as_uint(hi);
  a = (a + 0x7fffu + ((a >> 16) & 1u)) >> 16;
  b = (b + 0x7fffu + ((b >> 16) & 1u)) >> 16;
  return a | (b << 16);
}

// --------------------------- DWT + transpose -------------------------------
__global__ __launch_bounds__(256) void pre_k(const float* __restrict__ x,
                                             float* __restrict__ yL,
                                             float* __restrict__ yHH,
                                             float* __restrict__ hllh) {
  int gx = blockIdx.x;            // 2 (jt) * 4 (ci tile) = 8
  int jt = gx & 1, cit = gx >> 1;
  int i = blockIdx.y, b = blockIdx.z;
  int j0 = jt * 32, ci0 = cit * 32;
  int tx = threadIdx.x & 31, ty = threadIdx.x >> 5;
  __shared__ float sll[32][33], shl[32][33], slh[32][33], shh[32][33];
  const float2* x2 = (const float2*)x;
#pragma unroll
  for (int k = 0; k < 4; ++k) {
    int ci = ty + 8 * k;
    long base = (((long)b * 128 + ci0 + ci) * 128 + 2 * i) * 64 + j0 + tx;
    float2 ab = x2[base];
    float2 cd = x2[base + 64];
    float a = ab.x, bb = ab.y, c = cd.x, d = cd.y;
    sll[ci][tx] = (a + bb + c + d) * 0.5f;
    shl[ci][tx] = (a - bb + c - d) * 0.5f;
    slh[ci][tx] = (a + bb - c - d) * 0.5f;
    shh[ci][tx] = (a - bb - c + d) * 0.5f;
  }
  __syncthreads();
  long tok = (long)b * 4096 + i * 64 + j0;
#pragma unroll
  for (int k = 0; k < 4; ++k) {
    int row = ty + 8 * k;
    long t = tok + row;
    yL[t * 128 + ci0 + tx] = sll[tx][row];
    yHH[t * 128 + ci0 + tx] = shh[tx][row];
    hllh[t * 256 + ci0 + tx] = shl[tx][row];
    hllh[t * 256 + 128 + ci0 + tx] = slh[tx][row];
  }
}

// ------------------------------- GEMM (fp32) -------------------------------
template <bool BT, bool AEXP, bool BSCALE, int EPI>
__global__ __launch_bounds__(256) void gemm_k(
    const float* __restrict__ A, long sA, int lda,
    const float* __restrict__ B, long sB, int ldb,
    float* __restrict__ C, long sC, int ldc,
    int K, float alpha,
    const float* __restrict__ bias,
    const float* __restrict__ aux,
    const float* __restrict__ amax,
    const float* __restrict__ rls) {
  __shared__ float As[32][68];
  __shared__ float Bs[32][68];
  int z = blockIdx.z;
  const float* Ab = A + (long)z * sA;
  const float* Bb = B + (long)z * sB;
  float* Cb = C + (long)z * sC;
  int m0 = blockIdx.x * 64, n0 = blockIdx.y * 64;
  int tid = threadIdx.x;
  int tx = tid & 15, ty = tid >> 4;
  float acc[4][4] = {};
  for (int k0 = 0; k0 < K; k0 += 32) {
#pragma unroll
    for (int u = 0; u < 8; ++u) {
      int f = tid * 8 + u;
      int r = f >> 5, kk = f & 31;
      float v = Ab[(long)(m0 + r) * lda + k0 + kk];
      if (AEXP) v = __expf(v - amax[(long)z * 512 + k0 + kk]);
      As[kk][r] = v;
    }
    if (BT) {
#pragma unroll
      for (int u = 0; u < 8; ++u) {
        int f = tid * 8 + u;
        int r = f >> 5, kk = f & 31;
        Bs[kk][r] = Bb[(long)(n0 + r) * ldb + k0 + kk];
      }
    } else {
#pragma unroll
      for (int u = 0; u < 8; ++u) {
        int f = u * 256 + tid;
        int n = f & 63, kk = f >> 6;
        float v = Bb[(long)(k0 + kk) * ldb + n0 + n];
        if (BSCALE) v *= rls[(long)z * 512 + k0 + kk];
        Bs[kk][n] = v;
      }
    }
    __syncthreads();
#pragma unroll
    for (int kk = 0; kk < 32; ++kk) {
      float4 a4 = *(const float4*)&As[kk][ty * 4];
      float4 b4 = *(const float4*)&Bs[kk][tx * 4];
      acc[0][0] += a4.x * b4.x; acc[0][1] += a4.x * b4.y; acc[0][2] += a4.x * b4.z; acc[0][3] += a4.x * b4.w;
      acc[1][0] += a4.y * b4.x; acc[1][1] += a4.y * b4.y; acc[1][2] += a4.y * b4.z; acc[1][3] += a4.y * b4.w;
      acc[2][0] += a4.z * b4.x; acc[2][1] += a4.z * b4.y; acc[2][2] += a4.z * b4.z; acc[2][3] += a4.z * b4.w;
      acc[3][0] += a4.w * b4.x; acc[3][1] += a4.w * b4.y; acc[3][2] += a4.w * b4.z; acc[3][3] += a4.w * b4.w;
    }
    __syncthreads();
  }
#pragma unroll
  for (int i = 0; i < 4; ++i) {
    int m = m0 + ty * 4 + i;
#pragma unroll
    for (int j = 0; j < 4; ++j) {
      int n = n0 + tx * 4 + j;
      float v = acc[i][j] * alpha;
      if (bias) v += bias[n];
      if (EPI == EPI_GELU) v = gelu_f(v);
      else if (EPI == EPI_GELU_SUB) v = gelu_f(v) - aux[(long)m * ldc + n];
      else if (EPI == EPI_ADD) v += aux[(long)m * ldc + n];
      else if (EPI == EPI_SIGMOID) v = sigmoid_f(v);
      Cb[(long)m * ldc + n] = v;
    }
  }
}

// ---------------------- weight fp32 -> bf16 pre-convert --------------------
// OIHW flat order == [co][k=ci*16+kh*4+kw]: exactly the B-operand layout.
__global__ __launch_bounds__(256) void wcvt_k(const float* __restrict__ w,
                                              unsigned* __restrict__ wb) {
  int t = blockIdx.x * 256 + threadIdx.x;  // 512*256 = 131072 u32 = 262144 bf16
  wb[t] = f2bf_pk(w[2 * t], w[2 * t + 1]);
}

// ------------------ conv 4x4 s2 p1 as MFMA implicit GEMM -------------------
// Block: 128 tokens (2 output rows x 64 j) x 128 co. 4 waves (2x2), each
// 64x64 via 16x16x32 bf16 MFMA. K = 2048 in 32 chunks of 64 (4 ci).
__global__ __launch_bounds__(256) void conv4m_k(const float* __restrict__ x,
                                                const unsigned short* __restrict__ wb,
                                                const float* __restrict__ bias,
                                                float* __restrict__ dw) {
  __shared__ __align__(16) char smem[36864];
  char* As = smem;          // 128 rows x 144 B (64 bf16 + pad)
  char* Ws = smem + 18432;  // 128 rows x 144 B
  int ib = blockIdx.x, b = blockIdx.y;
  int tid = threadIdx.x;
  int lane = tid & 63, w = tid >> 6;
  int wm = w >> 1, wn = w & 1;
  int l15 = lane & 15, l4 = lane >> 4;
  f32x4 acc[4][4] = {};
  const float* xb = x + (long)b * 128 * 128 * 128;

  for (int ch = 0; ch < 32; ++ch) {
    if (ch) __syncthreads();
    // stage weights: 128 co x 64 k bf16, b128 in/out
    {
      int co = tid >> 1, half = tid & 1;
      const uint4* src = (const uint4*)(wb + (long)co * 2048 + ch * 64 + half * 32);
      uint4* dst = (uint4*)(Ws + co * 144 + half * 64);
#pragma unroll
      for (int u = 0; u < 4; ++u) dst[u] = src[u];
    }
    // build im2col A: per element group qp=(ci_loc,kh), 4 consecutive cols
#pragma unroll
    for (int it = 0; it < 8; ++it) {
      int f = tid + 256 * it;            // 128 m x 16 qp
      int m = f & 127, qp = f >> 7;
      int c = qp >> 2, kh = qp & 3;
      int oi = 2 * ib + (m >> 6);
      int gr = 2 * oi - 1 + kh;
      int col0 = 2 * (m & 63) - 1;
      const float* row = xb + ((long)(4 * ch + c) * 128 + gr) * 128;
      bool rok = (unsigned)gr < 128u;
      float v0 = (rok && (unsigned)col0 < 128u) ? row[col0] : 0.f;
      float v1 = (rok && (unsigned)(col0 + 1) < 128u) ? row[col0 + 1] : 0.f;
      float v2 = (rok && (unsigned)(col0 + 2) < 128u) ? row[col0 + 2] : 0.f;
      float v3 = (rok && (unsigned)(col0 + 3) < 128u) ? row[col0 + 3] : 0.f;
      uint2 pk;
      pk.x = f2bf_pk(v0, v1);
      pk.y = f2bf_pk(v2, v3);
      *(uint2*)(As + m * 144 + qp * 8) = pk;
    }
    __syncthreads();
#pragma unroll
    for (int s = 0; s < 2; ++s) {
      v8bf af[4], bfr[4];
#pragma unroll
      for (int t = 0; t < 4; ++t) {
        af[t] = *(const v8bf*)(As + (64 * wm + 16 * t + l15) * 144 + s * 64 + l4 * 16);
        bfr[t] = *(const v8bf*)(Ws + (64 * wn + 16 * t + l15) * 144 + s * 64 + l4 * 16);
      }
#pragma unroll
      for (int mt = 0; mt < 4; ++mt)
#pragma unroll
        for (int nt = 0; nt < 4; ++nt)
          acc[mt][nt] = __builtin_amdgcn_mfma_f32_16x16x32_bf16(af[mt], bfr[nt], acc[mt][nt], 0, 0, 0);
    }
  }
  // epilogue: bias+relu, LDS transpose, coalesced NCHW stores
  __syncthreads();
  float* buf = (float*)(smem + w * 4352);  // 16 x 65 f32 per wave
  int oi = 2 * ib + wm;
#pragma unroll
  for (int cg = 0; cg < 4; ++cg) {
    int co = 64 * wn + 16 * cg + l15;
    float bv = bias[co];
#pragma unroll
    for (int mt = 0; mt < 4; ++mt) {
      f32x4 a = acc[mt][cg];
#pragma unroll
      for (int r = 0; r < 4; ++r)
        buf[l15 * 65 + 16 * mt + 4 * l4 + r] = fmaxf(a[r] + bv, 0.f);
    }
    __syncthreads();
#pragma unroll
    for (int cr = 0; cr < 16; ++cr) {
      float vv = buf[cr * 65 + lane];
      dw[(((long)b * 128 + 64 * wn + 16 * cg + cr) * 64 + oi) * 64 + lane] = vv;
    }
    __syncthreads();
  }
}

// ------------------- attention column-softmax statistics -------------------
__global__ __launch_bounds__(256) void colmax_k(const float* __restrict__ S,
                                                float* __restrict__ cmax) {
  int z = blockIdx.y;
  int k = blockIdx.x * 256 + threadIdx.x;
  const float* Sb = S + (long)z * 262144;
  float m = -3.4e38f;
#pragma unroll 8
  for (int q = 0; q < 512; ++q) m = fmaxf(m, Sb[(long)q * 512 + k]);
  cmax[(long)z * 512 + k] = m;
}

__global__ __launch_bounds__(256) void expsum_k(const float* __restrict__ S,
                                                const float* __restrict__ cmax,
                                                float* __restrict__ recl) {
  int z = blockIdx.y;
  int k = blockIdx.x * 256 + threadIdx.x;
  const float* Sb = S + (long)z * 262144;
  float mx = cmax[(long)z * 512 + k];
  float s = 0.f;
#pragma unroll 8
  for (int q = 0; q < 512; ++q) s += __expf(Sb[(long)q * 512 + k] - mx);
  recl[(long)z * 512 + k] = 1.f / s;
}

// ------------------------------ layernorm ----------------------------------
__global__ __launch_bounds__(256) void ln_k(const float* __restrict__ X,
                                            const float* __restrict__ g,
                                            const float* __restrict__ bt,
                                            const float* __restrict__ gate,
                                            float* __restrict__ Y) {
  int t = (blockIdx.x * 256 + threadIdx.x) >> 6;
  int lane = threadIdx.x & 63;
  const float* xr = X + (long)t * 128;
  float v0 = xr[lane], v1 = xr[lane + 64];
  float s = v0 + v1, sq = v0 * v0 + v1 * v1;
#pragma unroll
  for (int off = 32; off > 0; off >>= 1) {
    s += __shfl_xor(s, off);
    sq += __shfl_xor(sq, off);
  }
  float mean = s * 0.0078125f;
  float var = sq * 0.0078125f - mean * mean;
  float rstd = rsqrtf(var + 1e-5f);
  float y0 = (v0 - mean) * rstd * g[lane] + bt[lane];
  float y1 = (v1 - mean) * rstd * g[lane + 64] + bt[lane + 64];
  if (gate) {
    y0 *= gate[(long)t * 128 + lane];
    y1 *= gate[(long)t * 128 + lane + 64];
  }
  Y[(long)t * 128 + lane] = y0;
  Y[(long)t * 128 + lane + 64] = y1;
}

// ------------------------------ combine ------------------------------------
__global__ __launch_bounds__(256) void combine_k(const float* __restrict__ attf,
                                                 const float* __restrict__ yt,
                                                 const float* __restrict__ dw,
                                                 const float* __restrict__ x,
                                                 float* __restrict__ out) {
  int gx = blockIdx.x;  // 2 (jt) * 4 (cot) = 8
  int jt = gx & 1, cot = gx >> 1;
  int i = blockIdx.y, b = blockIdx.z;
  int j0 = jt * 32, co0 = cot * 32;
  int tx = threadIdx.x & 31, ty = threadIdx.x >> 5;
  __shared__ float sa[32][33], sy[32][33];
  long tokbase = (long)b * 4096 + i * 64 + j0;
#pragma unroll
  for (int k = 0; k < 4; ++k) {
    int row = ty + 8 * k;
    long idx = (tokbase + row) * 128 + co0 + tx;
    sa[row][tx] = attf[idx];
    sy[row][tx] = yt[idx];
  }
  __syncthreads();
  float py = (float)(i * 127) / 63.0f;
  int y0 = (int)py;
  int y1 = min(y0 + 1, 127);
  float wy = py - (float)y0;
  int j = j0 + tx;
  float px = (float)(j * 127) / 63.0f;
  int x0 = (int)px;
  int x1 = min(x0 + 1, 127);
  float wx = px - (float)x0;
#pragma unroll
  for (int k = 0; k < 4; ++k) {
    int co = co0 + ty + 8 * k;
    const float* xb = x + (((long)b * 128 + co) * 128) * 128;
    float r0 = xb[y0 * 128 + x0] * (1.f - wx) + xb[y0 * 128 + x1] * wx;
    float r1 = xb[y1 * 128 + x0] * (1.f - wx) + xb[y1 * 128 + x1] * wx;
    float d2 = r0 * (1.f - wy) + r1 * wy;
    long oidx = (((long)b * 128 + co) * 64 + i) * 64 + j;
    float dwv = dw[oidx];
    float av = sa[tx][ty + 8 * k];
    float yv = sy[tx][ty + 8 * k];
    out[oidx] = av * (d2 - dwv) + yv;
  }
}

// ---------------------------------------------------------------------------
extern "C" void kernel_launch(void* const* d_in, const int* in_sizes, int n_in,
                              void* d_out, int out_size, void* d_ws, size_t ws_size,
                              hipStream_t stream) {
  const float* x = (const float*)d_in[0];
  const float* w1 = (const float*)d_in[1];
  const float* b1 = (const float*)d_in[2];
  const float* l1w = (const float*)d_in[3];
  const float* l1b = (const float*)d_in[4];
  const float* ln1g = (const float*)d_in[5];
  const float* ln1b = (const float*)d_in[6];
  const float* fc1w = (const float*)d_in[7];
  const float* fc1b = (const float*)d_in[8];
  const float* divw = (const float*)d_in[9];
  const float* divb = (const float*)d_in[10];
  const float* fc2w = (const float*)d_in[11];
  const float* fc2b = (const float*)d_in[12];
  const float* ln3g = (const float*)d_in[13];
  const float* ln3b = (const float*)d_in[14];
  const float* fc3aw = (const float*)d_in[15];
  const float* fc3ab = (const float*)d_in[16];
  const float* fc3bw = (const float*)d_in[17];
  const float* fc3bb = (const float*)d_in[18];
  const float* lnng = (const float*)d_in[19];
  const float* lnnb = (const float*)d_in[20];
  const float* actw = (const float*)d_in[21];
  const float* actb = (const float*)d_in[22];

  float* ws = (float*)d_ws;
  const long F = 8388608;  // 16*4096*128
  float* yL = ws;
  float* yHH = ws + F;
  float* y = ws + 2 * F;
  float* dw = ws + 3 * F;
  float* S = ws + 4 * F;
  float* hllh = ws + 4 * F;
  float* t2 = ws + 4 * F;
  float* t4 = ws + 5 * F;
  unsigned* wbf = (unsigned*)(ws + 6 * F);  // 512 KB bf16 weights; dead before S
  float* attO = ws + 8 * F;
  float* cmax = ws + 9 * F;
  float* recl = ws + 9 * F + 65536;
  float* t1 = yL;
  float* t3 = yHH;

  dim3 blk(256);
  const float qk_scale = 0.35355339059327373f;  // 8^-0.5

  // 1. DWT + transpose
  pre_k<<<dim3(8, 64, 16), blk, 0, stream>>>(x, yL, yHH, hllh);
  // 2. conv1 (1x1, 256->128)
  gemm_k<true, false, false, EPI_NONE><<<dim3(1024, 2, 1), blk, 0, stream>>>(
      hllh, 0, 256, w1, 0, 256, y, 0, 128, 256, 1.f, b1, nullptr, nullptr, nullptr);
  // 3. conv4x4 stride2 + relu (bf16 MFMA implicit GEMM)
  wcvt_k<<<dim3(512), blk, 0, stream>>>(l1w, wbf);
  conv4m_k<<<dim3(32, 16), blk, 0, stream>>>(x, (const unsigned short*)wbf, l1b, dw);
  // 4. S = (yL @ y^T) * scale
  gemm_k<true, false, false, EPI_NONE><<<dim3(8, 8, 128), blk, 0, stream>>>(
      yL, 65536, 128, y, 65536, 128, S, 262144, 512, 128, qk_scale,
      nullptr, nullptr, nullptr, nullptr);
  // 5. column (q-axis) softmax stats
  colmax_k<<<dim3(2, 128), blk, 0, stream>>>(S, cmax);
  expsum_k<<<dim3(2, 128), blk, 0, stream>>>(S, cmax, recl);
  // 6. attO = exp(S - m_k) @ (V * 1/l_k)
  gemm_k<false, true, true, EPI_NONE><<<dim3(8, 2, 128), blk, 0, stream>>>(
      S, 262144, 512, yHH, 65536, 128, attO, 65536, 128, 512, 1.f,
      nullptr, nullptr, cmax, recl);
  // 7. FFN
  ln_k<<<16384, blk, 0, stream>>>(attO, ln1g, ln1b, nullptr, t1);
  gemm_k<true, false, false, EPI_GELU><<<dim3(1024, 2, 1), blk, 0, stream>>>(
      t1, 0, 128, fc1w, 0, 128, t2, 0, 128, 128, 1.f, fc1b, nullptr, nullptr, nullptr);
  gemm_k<true, false, false, EPI_GELU_SUB><<<dim3(1024, 2, 1), blk, 0, stream>>>(
      attO, 0, 128, divw, 0, 128, t3, 0, 128, 128, 1.f, divb, t2, nullptr, nullptr);
  gemm_k<true, false, false, EPI_GELU><<<dim3(1024, 2, 1), blk, 0, stream>>>(
      t3, 0, 128, fc2w, 0, 128, t4, 0, 128, 128, 1.f, fc2b, nullptr, nullptr, nullptr);
  ln_k<<<16384, blk, 0, stream>>>(attO, ln3g, ln3b, nullptr, t1);
  gemm_k<true, false, false, EPI_GELU><<<dim3(1024, 2, 1), blk, 0, stream>>>(
      t1, 0, 128, fc3aw, 0, 128, t3, 0, 128, 128, 1.f, fc3ab, nullptr, nullptr, nullptr);
  gemm_k<true, false, false, EPI_ADD><<<dim3(1024, 2, 1), blk, 0, stream>>>(
      t3, 0, 128, fc3bw, 0, 128, t1, 0, 128, 128, 1.f, fc3bb, t4, nullptr, nullptr);
  gemm_k<true, false, false, EPI_SIGMOID><<<dim3(1024, 2, 1), blk, 0, stream>>>(
      attO, 0, 128, actw, 0, 128, t3, 0, 128, 128, 1.f, actb, nullptr, nullptr, nullptr);
  ln_k<<<16384, blk, 0, stream>>>(t1, lnng, lnnb, t3, t2);
  // 8. combine
  combine_k<<<dim3(8, 64, 16), blk, 0, stream>>>(t2, y, dw, x, (float*)d_out);
}

// Round 3
// 756.155 us; speedup vs baseline: 4.2102x; 1.5569x over previous
//
#include <hip/hip_runtime.h>
#include <cmath>

// ---------------------------------------------------------------------------
// Down_42468636623217 — round 2: full bf16-MFMA pipeline.
//  - gemm16_k: unified bf16 MFMA GEMM (128x128 tile, BK=64, XOR-swizzled LDS,
//    register-prefetch pipeline), epilogues incl. exp (QK softmax numerator).
//  - attention: col-softmax = sum pass over E=exp(S) bf16; 1/sum folded into
//    PV A-loader. pre_k emits yHH^T so PV B is a plain N x K operand.
//  - conv4m: register-prefetch pipelined, bf16 out.
// ---------------------------------------------------------------------------

#define EPI_NONE 0
#define EPI_GELU 1
#define EPI_GELU_SUB 2
#define EPI_ADD 3
#define EPI_SIGMOID 4
#define EPI_EXP 5

typedef unsigned short u16;
typedef __bf16 v8bf __attribute__((ext_vector_type(8)));
typedef float f32x4 __attribute__((ext_vector_type(4)));

__device__ __forceinline__ float gelu_f(float v) {
  return 0.5f * v * (1.f + erff(v * 0.70710678118654752f));
}
__device__ __forceinline__ float sigmoid_f(float v) {
  return 1.f / (1.f + __expf(-v));
}
__device__ __forceinline__ float bf2f(u16 h) {
  return __uint_as_float((unsigned)h << 16);
}
__device__ __forceinline__ u16 f2bf(float f) {
  unsigned u = __float_as_uint(f);
  return (u16)((u + 0x7fffu + ((u >> 16) & 1u)) >> 16);
}
__device__ __forceinline__ unsigned f2bf_pk(float lo, float hi) {
  unsigned a = __float_as_uint(lo), b = __float_as_uint(hi);
  a = (a + 0x7fffu + ((a >> 16) & 1u)) >> 16;
  b = (b + 0x7fffu + ((b >> 16) & 1u)) >> 16;
  return a | (b << 16);
}

// --------------------------- DWT + transpose -------------------------------
// x NCHW fp32 -> yL16 [t][c] bf16, hllh16 [t][256] bf16, yHHt16 [c][t] bf16.
__global__ __launch_bounds__(256) void pre_k(const float* __restrict__ x,
                                             u16* __restrict__ yL16,
                                             u16* __restrict__ yHHt16,
                                             u16* __restrict__ hllh16) {
  int gx = blockIdx.x;  // 2 (jt) * 4 (ci tile) = 8
  int jt = gx & 1, cit = gx >> 1;
  int i = blockIdx.y, b = blockIdx.z;
  int j0 = jt * 32, ci0 = cit * 32;
  int tx = threadIdx.x & 31, ty = threadIdx.x >> 5;
  __shared__ float sll[32][33], shl[32][33], slh[32][33], shh[32][33];
  const float2* x2 = (const float2*)x;
#pragma unroll
  for (int k = 0; k < 4; ++k) {
    int ci = ty + 8 * k;
    long base = (((long)b * 128 + ci0 + ci) * 128 + 2 * i) * 64 + j0 + tx;
    float2 ab = x2[base];
    float2 cd = x2[base + 64];
    float a = ab.x, bb = ab.y, c = cd.x, d = cd.y;
    sll[ci][tx] = (a + bb + c + d) * 0.5f;
    shl[ci][tx] = (a - bb + c - d) * 0.5f;
    slh[ci][tx] = (a + bb - c - d) * 0.5f;
    shh[ci][tx] = (a - bb - c + d) * 0.5f;
  }
  __syncthreads();
  long tok = (long)b * 4096 + i * 64 + j0;
#pragma unroll
  for (int k = 0; k < 4; ++k) {
    int row = ty + 8 * k;
    long t = tok + row;
    yL16[t * 128 + ci0 + tx] = f2bf(sll[tx][row]);
    hllh16[t * 256 + ci0 + tx] = f2bf(shl[tx][row]);
    hllh16[t * 256 + 128 + ci0 + tx] = f2bf(slh[tx][row]);
    // transposed HH: row = channel, tx = token
    yHHt16[(long)(ci0 + row) * 65536 + tok + tx] = f2bf(shh[row][tx]);
  }
}

// ---------------------- weights fp32 -> bf16 (one pass) --------------------
// wall layout (elems): l1w@0(262144) w1@262144(32768) fc1@294912 div@311296
//                      fc2@327680 fc3a@344064 fc3b@360448 act@376832
__global__ __launch_bounds__(256) void wcvt8_k(
    const float* __restrict__ a0, const float* __restrict__ a1,
    const float* __restrict__ a2, const float* __restrict__ a3,
    const float* __restrict__ a4, const float* __restrict__ a5,
    const float* __restrict__ a6, const float* __restrict__ a7,
    unsigned* __restrict__ dst) {
  int f = blockIdx.x * 256 + threadIdx.x;  // 196608 uints
  int e = 2 * f;
  const float* s; int b;
  if (e < 262144)      { s = a0; b = 0; }
  else if (e < 294912) { s = a1; b = 262144; }
  else if (e < 311296) { s = a2; b = 294912; }
  else if (e < 327680) { s = a3; b = 311296; }
  else if (e < 344064) { s = a4; b = 327680; }
  else if (e < 360448) { s = a5; b = 344064; }
  else if (e < 376832) { s = a6; b = 360448; }
  else                 { s = a7; b = 376832; }
  dst[f] = f2bf_pk(s[e - b], s[e - b + 1]);
}

// --------------------------- unified bf16 GEMM -----------------------------
// C[m,n] = epi(alpha * sum_k A[m,k]*B[n,k] + bias[n]); A: MxK, B: NxK bf16.
// AMODE 1: A element scaled by sc[z*K + k] (PV: 1/l_k fold).
// Tile 128x128, BK=64, 4 waves 2x2 (each 64x64, 16x16x32 MFMA), XOR-swizzle.
template <int AMODE, int EPI>
__global__ __launch_bounds__(256) void gemm16_k(
    const u16* __restrict__ A, long sA, int lda,
    const u16* __restrict__ B, long sB, int ldb,
    u16* __restrict__ C, long sC, int ldc,
    int K, float alpha, const float* __restrict__ bias,
    const u16* __restrict__ aux, const float* __restrict__ sc) {
  __shared__ __align__(16) char smem[32768];
  char* As = smem;
  char* Bs = smem + 16384;
  int z = blockIdx.z;
  int tid = threadIdx.x, lane = tid & 63, w = tid >> 6;
  int wm = w >> 1, wn = w & 1, l15 = lane & 15, l4 = lane >> 4;
  const u16* Ab = A + (long)z * sA + (long)blockIdx.x * 128 * lda;
  const u16* Bb = B + (long)z * sB + (long)blockIdx.y * 128 * ldb;
  const float* scz = (AMODE == 1) ? sc + (long)z * K : nullptr;
  int sm = tid >> 3, skg = tid & 7;
  int sbase = sm * 128 + ((skg ^ (sm & 7)) << 4);
  uint4 pa[4], pb[4];

  auto loadAB = [&](int k0) {
#pragma unroll
    for (int u = 0; u < 4; ++u) {
      pb[u] = *(const uint4*)(Bb + (long)(sm + 32 * u) * ldb + k0 + skg * 8);
      uint4 v = *(const uint4*)(Ab + (long)(sm + 32 * u) * lda + k0 + skg * 8);
      if (AMODE == 1) {
        float4 s0 = *(const float4*)(scz + k0 + skg * 8);
        float4 s1 = *(const float4*)(scz + k0 + skg * 8 + 4);
        v.x = f2bf_pk(bf2f((u16)(v.x & 0xffff)) * s0.x, bf2f((u16)(v.x >> 16)) * s0.y);
        v.y = f2bf_pk(bf2f((u16)(v.y & 0xffff)) * s0.z, bf2f((u16)(v.y >> 16)) * s0.w);
        v.z = f2bf_pk(bf2f((u16)(v.z & 0xffff)) * s1.x, bf2f((u16)(v.z >> 16)) * s1.y);
        v.w = f2bf_pk(bf2f((u16)(v.w & 0xffff)) * s1.z, bf2f((u16)(v.w >> 16)) * s1.w);
      }
      pa[u] = v;
    }
  };

  f32x4 acc[4][4] = {};
  loadAB(0);
  int nch = K >> 6;
  for (int ch = 0; ch < nch; ++ch) {
    __syncthreads();
#pragma unroll
    for (int u = 0; u < 4; ++u) {
      *(uint4*)(As + sbase + u * 4096) = pa[u];
      *(uint4*)(Bs + sbase + u * 4096) = pb[u];
    }
    __syncthreads();
    if (ch + 1 < nch) loadAB((ch + 1) << 6);
#pragma unroll
    for (int s = 0; s < 2; ++s) {
      int ko = (((s << 2) | l4) ^ (l15 & 7)) << 4;
      v8bf af[4], bfr[4];
#pragma unroll
      for (int t = 0; t < 4; ++t) {
        af[t] = *(const v8bf*)(As + (64 * wm + 16 * t + l15) * 128 + ko);
        bfr[t] = *(const v8bf*)(Bs + (64 * wn + 16 * t + l15) * 128 + ko);
      }
#pragma unroll
      for (int mt = 0; mt < 4; ++mt)
#pragma unroll
        for (int nt = 0; nt < 4; ++nt)
          acc[mt][nt] = __builtin_amdgcn_mfma_f32_16x16x32_bf16(af[mt], bfr[nt], acc[mt][nt], 0, 0, 0);
    }
  }
  // epilogue: C/D layout col = lane&15 (n), row = (lane>>4)*4 + reg (m)
  u16* Cb = C + (long)z * sC;
#pragma unroll
  for (int mt = 0; mt < 4; ++mt) {
#pragma unroll
    for (int nt = 0; nt < 4; ++nt) {
      f32x4 a = acc[mt][nt];
      int n = blockIdx.y * 128 + 64 * wn + 16 * nt + l15;
      float bv = bias ? bias[n] : 0.f;
#pragma unroll
      for (int r = 0; r < 4; ++r) {
        long m = (long)blockIdx.x * 128 + 64 * wm + 16 * mt + 4 * l4 + r;
        float v = a[r] * alpha + bv;
        if (EPI == EPI_GELU) v = gelu_f(v);
        else if (EPI == EPI_GELU_SUB) v = gelu_f(v) - bf2f(aux[m * ldc + n]);
        else if (EPI == EPI_ADD) v += bf2f(aux[m * ldc + n]);
        else if (EPI == EPI_SIGMOID) v = sigmoid_f(v);
        else if (EPI == EPI_EXP) v = __expf(v);
        Cb[m * ldc + n] = f2bf(v);
      }
    }
  }
}

// ------------------ conv 4x4 s2 p1 as MFMA implicit GEMM -------------------
// Register-prefetch pipelined; bf16 output.
__global__ __launch_bounds__(256) void conv4m_k(const float* __restrict__ x,
                                                const u16* __restrict__ wb,
                                                const float* __restrict__ bias,
                                                u16* __restrict__ dw16) {
  __shared__ __align__(16) char smem[36864];
  char* As = smem;          // 128 rows x 144 B
  char* Ws = smem + 18432;  // 128 rows x 144 B
  int ib = blockIdx.x, b = blockIdx.y;
  int tid = threadIdx.x;
  int lane = tid & 63, w = tid >> 6;
  int wm = w >> 1, wn = w & 1;
  int l15 = lane & 15, l4 = lane >> 4;
  f32x4 acc[4][4] = {};
  const float* xb = x + (long)b * 128 * 128 * 128;

  // per-thread constants for im2col build: m = tid&127 fixed, qp = qp0 + 2*it
  int m = tid & 127, qp0 = tid >> 7;
  int col0 = 2 * (m & 63) - 1;
  int oi_a = 2 * ib + (m >> 6);
  int groff = 2 * oi_a - 1;
  bool c0ok = (m & 63) != 0;
  bool c3ok = (m & 63) != 63;
  int awo[8];
#pragma unroll
  for (int it = 0; it < 8; ++it) awo[it] = m * 144 + (qp0 + 2 * it) * 8;
  const u16* wgbase = wb + (long)(tid >> 1) * 2048 + (tid & 1) * 32;
  int wro = (tid >> 1) * 144 + (tid & 1) * 64;

  uint4 wreg[4];
  uint2 areg[8];
  auto preW = [&](int ch) {
    const uint4* src = (const uint4*)(wgbase + ch * 64);
#pragma unroll
    for (int u = 0; u < 4; ++u) wreg[u] = src[u];
  };
  auto preA = [&](int ch) {
#pragma unroll
    for (int it = 0; it < 8; ++it) {
      int qp = qp0 + 2 * it;
      int c = qp >> 2, kh = qp & 3;
      int gr = groff + kh;
      const float* row = xb + ((long)(4 * ch + c) * 128 + gr) * 128;
      bool rok = (unsigned)gr < 128u;
      float v0 = (rok && c0ok) ? row[col0] : 0.f;
      float v1 = rok ? row[col0 + 1] : 0.f;
      float v2 = rok ? row[col0 + 2] : 0.f;
      float v3 = (rok && c3ok) ? row[col0 + 3] : 0.f;
      areg[it].x = f2bf_pk(v0, v1);
      areg[it].y = f2bf_pk(v2, v3);
    }
  };

  preW(0);
  preA(0);
  for (int ch = 0; ch < 32; ++ch) {
    __syncthreads();
    {
      uint4* dst = (uint4*)(Ws + wro);
#pragma unroll
      for (int u = 0; u < 4; ++u) dst[u] = wreg[u];
#pragma unroll
      for (int it = 0; it < 8; ++it) *(uint2*)(As + awo[it]) = areg[it];
    }
    __syncthreads();
    if (ch < 31) { preW(ch + 1); preA(ch + 1); }
#pragma unroll
    for (int s = 0; s < 2; ++s) {
      v8bf af[4], bfr[4];
#pragma unroll
      for (int t = 0; t < 4; ++t) {
        af[t] = *(const v8bf*)(As + (64 * wm + 16 * t + l15) * 144 + s * 64 + l4 * 16);
        bfr[t] = *(const v8bf*)(Ws + (64 * wn + 16 * t + l15) * 144 + s * 64 + l4 * 16);
      }
#pragma unroll
      for (int mt = 0; mt < 4; ++mt)
#pragma unroll
        for (int nt = 0; nt < 4; ++nt)
          acc[mt][nt] = __builtin_amdgcn_mfma_f32_16x16x32_bf16(af[mt], bfr[nt], acc[mt][nt], 0, 0, 0);
    }
  }
  // epilogue: bias+relu, LDS transpose, coalesced bf16 NCHW stores
  __syncthreads();
  float* buf = (float*)(smem + w * 4352);  // 16 x 65 f32 per wave
  int oi = 2 * ib + wm;
#pragma unroll
  for (int cg = 0; cg < 4; ++cg) {
    int co = 64 * wn + 16 * cg + l15;
    float bv = bias[co];
#pragma unroll
    for (int mt = 0; mt < 4; ++mt) {
      f32x4 a = acc[mt][cg];
#pragma unroll
      for (int r = 0; r < 4; ++r)
        buf[l15 * 65 + 16 * mt + 4 * l4 + r] = fmaxf(a[r] + bv, 0.f);
    }
    __syncthreads();
#pragma unroll
    for (int cr = 0; cr < 16; ++cr) {
      dw16[(((long)b * 128 + 64 * wn + 16 * cg + cr) * 64 + oi) * 64 + lane] =
          f2bf(buf[cr * 65 + lane]);
    }
    __syncthreads();
  }
}

// --------------- attention column normalizer: sc = 1/sum_q E ---------------
__global__ __launch_bounds__(256) void ssum_k(const u16* __restrict__ E,
                                              float* __restrict__ sc) {
  int z = blockIdx.y;
  int k = blockIdx.x * 256 + threadIdx.x;
  const u16* Eb = E + (long)z * 262144 + k;
  float s = 0.f;
#pragma unroll 8
  for (int q = 0; q < 512; ++q) s += bf2f(Eb[(long)q * 512]);
  sc[(long)z * 512 + k] = 1.f / s;
}

// ------------------------------ layernorm (bf16) ---------------------------
__global__ __launch_bounds__(256) void ln16_k(const u16* __restrict__ X,
                                              const float* __restrict__ g,
                                              const float* __restrict__ bt,
                                              const u16* __restrict__ gate,
                                              u16* __restrict__ Y) {
  int t = (blockIdx.x * 256 + threadIdx.x) >> 6;
  int lane = threadIdx.x & 63;
  const u16* xr = X + (long)t * 128;
  float v0 = bf2f(xr[lane]), v1 = bf2f(xr[lane + 64]);
  float s = v0 + v1, sq = v0 * v0 + v1 * v1;
#pragma unroll
  for (int off = 32; off > 0; off >>= 1) {
    s += __shfl_xor(s, off);
    sq += __shfl_xor(sq, off);
  }
  float mean = s * 0.0078125f;
  float var = sq * 0.0078125f - mean * mean;
  float rstd = rsqrtf(var + 1e-5f);
  float y0 = (v0 - mean) * rstd * g[lane] + bt[lane];
  float y1 = (v1 - mean) * rstd * g[lane + 64] + bt[lane + 64];
  if (gate) {
    y0 *= bf2f(gate[(long)t * 128 + lane]);
    y1 *= bf2f(gate[(long)t * 128 + lane + 64]);
  }
  Y[(long)t * 128 + lane] = f2bf(y0);
  Y[(long)t * 128 + lane + 64] = f2bf(y1);
}

// ------------------------------ combine ------------------------------------
__global__ __launch_bounds__(256) void combine_k(const u16* __restrict__ attf,
                                                 const u16* __restrict__ yt,
                                                 const u16* __restrict__ dw16,
                                                 const float* __restrict__ x,
                                                 float* __restrict__ out) {
  int gx = blockIdx.x;  // 2 (jt) * 4 (cot) = 8
  int jt = gx & 1, cot = gx >> 1;
  int i = blockIdx.y, b = blockIdx.z;
  int j0 = jt * 32, co0 = cot * 32;
  int tx = threadIdx.x & 31, ty = threadIdx.x >> 5;
  __shared__ float sa[32][33], sy[32][33];
  long tokbase = (long)b * 4096 + i * 64 + j0;
#pragma unroll
  for (int k = 0; k < 4; ++k) {
    int row = ty + 8 * k;
    long idx = (tokbase + row) * 128 + co0 + tx;
    sa[row][tx] = bf2f(attf[idx]);
    sy[row][tx] = bf2f(yt[idx]);
  }
  __syncthreads();
  float py = (float)(i * 127) / 63.0f;
  int y0 = (int)py;
  int y1 = min(y0 + 1, 127);
  float wy = py - (float)y0;
  int j = j0 + tx;
  float px = (float)(j * 127) / 63.0f;
  int x0 = (int)px;
  int x1 = min(x0 + 1, 127);
  float wx = px - (float)x0;
#pragma unroll
  for (int k = 0; k < 4; ++k) {
    int co = co0 + ty + 8 * k;
    const float* xb = x + (((long)b * 128 + co) * 128) * 128;
    float r0 = xb[y0 * 128 + x0] * (1.f - wx) + xb[y0 * 128 + x1] * wx;
    float r1 = xb[y1 * 128 + x0] * (1.f - wx) + xb[y1 * 128 + x1] * wx;
    float d2 = r0 * (1.f - wy) + r1 * wy;
    long oidx = (((long)b * 128 + co) * 64 + i) * 64 + j;
    float dwv = bf2f(dw16[oidx]);
    out[oidx] = sa[tx][ty + 8 * k] * (d2 - dwv) + sy[tx][ty + 8 * k];
  }
}

// ---------------------------------------------------------------------------
extern "C" void kernel_launch(void* const* d_in, const int* in_sizes, int n_in,
                              void* d_out, int out_size, void* d_ws, size_t ws_size,
                              hipStream_t stream) {
  const float* x = (const float*)d_in[0];
  const float* w1 = (const float*)d_in[1];
  const float* b1 = (const float*)d_in[2];
  const float* l1w = (const float*)d_in[3];
  const float* l1b = (const float*)d_in[4];
  const float* ln1g = (const float*)d_in[5];
  const float* ln1b = (const float*)d_in[6];
  const float* fc1w = (const float*)d_in[7];
  const float* fc1b = (const float*)d_in[8];
  const float* divw = (const float*)d_in[9];
  const float* divb = (const float*)d_in[10];
  const float* fc2w = (const float*)d_in[11];
  const float* fc2b = (const float*)d_in[12];
  const float* ln3g = (const float*)d_in[13];
  const float* ln3b = (const float*)d_in[14];
  const float* fc3aw = (const float*)d_in[15];
  const float* fc3ab = (const float*)d_in[16];
  const float* fc3bw = (const float*)d_in[17];
  const float* fc3bb = (const float*)d_in[18];
  const float* lnng = (const float*)d_in[19];
  const float* lnnb = (const float*)d_in[20];
  const float* actw = (const float*)d_in[21];
  const float* actb = (const float*)d_in[22];

  char* W = (char*)d_ws;
  u16* yL16 = (u16*)(W);
  u16* hllh16 = (u16*)(W + 16777216L);
  u16* yHHt16 = (u16*)(W + 50331648L);
  u16* y16 = (u16*)(W + 67108864L);
  u16* S16 = (u16*)(W + 83886080L);
  u16* attO16 = (u16*)(W + 150994944L);
  u16* dw16 = (u16*)(W + 167772160L);
  u16* t1 = (u16*)(W + 184549376L);
  u16* t2 = (u16*)(W + 201326592L);
  u16* t3 = (u16*)(W + 218103808L);
  u16* t4 = (u16*)(W + 234881024L);
  float* sc = (float*)(W + 251658240L);
  u16* wall = (u16*)(W + 251920384L);
  u16* l1wb = wall;
  u16* w1b = wall + 262144;
  u16* fc1b16 = wall + 294912;
  u16* divb16 = wall + 311296;
  u16* fc2b16 = wall + 327680;
  u16* fc3ab16 = wall + 344064;
  u16* fc3bb16 = wall + 360448;
  u16* actb16 = wall + 376832;

  dim3 blk(256);
  const float qk_scale = 0.35355339059327373f;  // 8^-0.5

  wcvt8_k<<<dim3(768), blk, 0, stream>>>(l1w, w1, fc1w, divw, fc2w, fc3aw,
                                         fc3bw, actw, (unsigned*)wall);
  // 1. DWT + transpose (bf16 outputs, incl. yHH^T)
  pre_k<<<dim3(8, 64, 16), blk, 0, stream>>>(x, yL16, yHHt16, hllh16);
  // 2. conv1 (1x1, 256->128): y16 = hllh @ w1^T + b1
  gemm16_k<0, EPI_NONE><<<dim3(512, 1, 1), blk, 0, stream>>>(
      hllh16, 0, 256, w1b, 0, 256, y16, 0, 128, 256, 1.f, b1, nullptr, nullptr);
  // 3. conv4x4 stride2 + relu (pipelined bf16 MFMA implicit GEMM)
  conv4m_k<<<dim3(32, 16), blk, 0, stream>>>(x, l1wb, l1b, dw16);
  // 4. E = exp(scale * yL @ y^T)  (softmax numerator, stored bf16)
  gemm16_k<0, EPI_EXP><<<dim3(4, 4, 128), blk, 0, stream>>>(
      yL16, 65536, 128, y16, 65536, 128, S16, 262144, 512, 128, qk_scale,
      nullptr, nullptr, nullptr);
  // 5. sc_k = 1 / sum_q E
  ssum_k<<<dim3(2, 128), blk, 0, stream>>>(S16, sc);
  // 6. attO = (E * sc) @ yHH   (scale folded into A-loader, B = yHH^T rows)
  gemm16_k<1, EPI_NONE><<<dim3(4, 1, 128), blk, 0, stream>>>(
      S16, 262144, 512, yHHt16, 512, 65536, attO16, 65536, 128, 512, 1.f,
      nullptr, nullptr, sc);
  // 7. FFN
  ln16_k<<<16384, blk, 0, stream>>>(attO16, ln1g, ln1b, nullptr, t1);
  gemm16_k<0, EPI_GELU><<<dim3(512, 1, 1), blk, 0, stream>>>(
      t1, 0, 128, fc1b16, 0, 128, t2, 0, 128, 128, 1.f, fc1b, nullptr, nullptr);
  gemm16_k<0, EPI_GELU_SUB><<<dim3(512, 1, 1), blk, 0, stream>>>(
      attO16, 0, 128, divb16, 0, 128, t3, 0, 128, 128, 1.f, divb, t2, nullptr);
  gemm16_k<0, EPI_GELU><<<dim3(512, 1, 1), blk, 0, stream>>>(
      t3, 0, 128, fc2b16, 0, 128, t4, 0, 128, 128, 1.f, fc2b, nullptr, nullptr);
  ln16_k<<<16384, blk, 0, stream>>>(attO16, ln3g, ln3b, nullptr, t1);
  gemm16_k<0, EPI_GELU><<<dim3(512, 1, 1), blk, 0, stream>>>(
      t1, 0, 128, fc3ab16, 0, 128, t3, 0, 128, 128, 1.f, fc3ab, nullptr, nullptr);
  gemm16_k<0, EPI_ADD><<<dim3(512, 1, 1), blk, 0, stream>>>(
      t3, 0, 128, fc3bb16, 0, 128, t1, 0, 128, 128, 1.f, fc3bb, t4, nullptr);
  gemm16_k<0, EPI_SIGMOID><<<dim3(512, 1, 1), blk, 0, stream>>>(
      attO16, 0, 128, actb16, 0, 128, t3, 0, 128, 128, 1.f, actb, nullptr, nullptr);
  ln16_k<<<16384, blk, 0, stream>>>(t1, lnng, lnnb, t3, t2);
  // 8. combine: out = attf * (resize(x) - dw) + y
  combine_k<<<dim3(8, 64, 16), blk, 0, stream>>>(t2, y16, dw16, x, (float*)d_out);
}